// Round 1
// baseline (49.342 us; speedup 1.0000x reference)
//
#include <hip/hip_runtime.h>
#include <cmath>

constexpr int   DIM   = 2048;
constexpr int   NEXP  = 4;
constexpr float EPS   = 1e-6f;
constexpr float SCALE = 3.0f;

// One wave (64 lanes) per row. Each lane covers 32 elements of the row
// (8 x float4 at d = k*256 + lane*4). Fused router weight rw[e][d]*nw[d]
// is held in registers (4 experts x 8 float4 = 128 VGPR) and amortized
// across grid-strided rows. 5 partials (sumsq + 4 dots) reduced with a
// 64-lane xor-shuffle butterfly; lane 0 computes tanh and stores float4.
__global__ __launch_bounds__(256, 2)
void altup_router_kernel(const float* __restrict__ x,
                         const float* __restrict__ nw,
                         const float* __restrict__ rw,
                         float* __restrict__ out,
                         int nrows)
{
    const int lane          = threadIdx.x & 63;
    const int wid_in_blk    = threadIdx.x >> 6;
    const int waves_per_blk = blockDim.x >> 6;
    const int nwaves        = gridDim.x * waves_per_blk;
    const int wave          = blockIdx.x * waves_per_blk + wid_in_blk;

    const int base = lane * 4;  // float offset inside each 256-float chunk

    // Preload fused weights: w[e][k] = rw[e*DIM + d] * nw[d]
    float4 w[NEXP][8];
#pragma unroll
    for (int e = 0; e < NEXP; ++e) {
#pragma unroll
        for (int k = 0; k < 8; ++k) {
            const int d = k * 256 + base;
            const float4 r = *reinterpret_cast<const float4*>(rw + e * DIM + d);
            const float4 n = *reinterpret_cast<const float4*>(nw + d);
            w[e][k] = make_float4(r.x * n.x, r.y * n.y, r.z * n.z, r.w * n.w);
        }
    }

    for (int row = wave; row < nrows; row += nwaves) {
        const float* xr = x + (size_t)row * DIM;

        float acc[5] = {0.f, 0.f, 0.f, 0.f, 0.f};  // sumsq, dot0..3
#pragma unroll
        for (int k = 0; k < 8; ++k) {
            const float4 xv = *reinterpret_cast<const float4*>(xr + k * 256 + base);

            acc[0] = fmaf(xv.x, xv.x, acc[0]);
            acc[0] = fmaf(xv.y, xv.y, acc[0]);
            acc[0] = fmaf(xv.z, xv.z, acc[0]);
            acc[0] = fmaf(xv.w, xv.w, acc[0]);
#pragma unroll
            for (int e = 0; e < NEXP; ++e) {
                acc[1 + e] = fmaf(xv.x, w[e][k].x, acc[1 + e]);
                acc[1 + e] = fmaf(xv.y, w[e][k].y, acc[1 + e]);
                acc[1 + e] = fmaf(xv.z, w[e][k].z, acc[1 + e]);
                acc[1 + e] = fmaf(xv.w, w[e][k].w, acc[1 + e]);
            }
        }

        // 64-lane butterfly reduction of the 5 partials
#pragma unroll
        for (int m = 32; m >= 1; m >>= 1) {
#pragma unroll
            for (int i = 0; i < 5; ++i)
                acc[i] += __shfl_xor(acc[i], m, 64);
        }

        if (lane == 0) {
            const float inv_rms = rsqrtf(acc[0] * (1.0f / DIM) + EPS);
            float4 o;
            o.x = tanhf(acc[1] * inv_rms * SCALE);
            o.y = tanhf(acc[2] * inv_rms * SCALE);
            o.z = tanhf(acc[3] * inv_rms * SCALE);
            o.w = tanhf(acc[4] * inv_rms * SCALE);
            reinterpret_cast<float4*>(out)[row] = o;
        }
    }
}

extern "C" void kernel_launch(void* const* d_in, const int* in_sizes, int n_in,
                              void* d_out, int out_size, void* d_ws, size_t ws_size,
                              hipStream_t stream)
{
    const float* x   = (const float*)d_in[0];  // (4, 8192, 2048) f32
    const float* nw  = (const float*)d_in[1];  // (2048,) f32
    const float* rw  = (const float*)d_in[2];  // (4, 2048) f32
    float*       out = (float*)d_out;          // (4, 8192, 4) f32

    const int nrows = in_sizes[0] / DIM;       // 32768

    // Target ~8 rows per wave; cap at 1024 blocks (4 waves each).
    int waves_needed  = (nrows + 7) / 8;
    int blocks        = (waves_needed + 3) / 4;
    if (blocks > 1024) blocks = 1024;
    if (blocks < 1)    blocks = 1;

    hipLaunchKernelGGL(altup_router_kernel, dim3(blocks), dim3(256), 0, stream,
                       x, nw, rw, out, nrows);
}